// Round 1
// baseline (46031.488 us; speedup 1.0000x reference)
//
#include <hip/hip_runtime.h>
#include <math.h>

#define NCHAR 256
#define NHID 2048
#define NSTACK 32
#define STACK 512
#define DEPTH 4
#define T 4096
#define NB 128          // persistent blocks (all co-resident: 128 <= 256 CUs)
#define BT 512          // threads/block (8 waves)
#define RPB 16          // rows of hid2hid per block
#define LG 128          // 96 act logits + 32 top_val logits

// ---------------- sequential persistent kernel ----------------
__global__ __launch_bounds__(BT) void stackrnn_seq(
    const int* __restrict__ tokens,
    const float* __restrict__ in2hid,    // [NHID][NCHAR]
    const float* __restrict__ hid2hid,   // [NHID][NHID]
    const float* __restrict__ hid2act,   // [NSTACK][3][NHID]
    const float* __restrict__ hid2stack, // [NSTACK][STACK][NHID]
    const float* __restrict__ stack2hid, // [NSTACK][NHID][STACK]
    const float* __restrict__ hid2out,   // [NCHAR][NHID]
    float* __restrict__ out,             // [T][NCHAR] logits (softmaxed later)
    float* __restrict__ Hbuf,            // [T][NHID]
    float* __restrict__ stbuf,           // [2][NSTACK*STACK]
    float* __restrict__ Lmid,            // [3][LG][8]  rotating logit accumulators
    int*   __restrict__ flags)           // [NB]
{
  __shared__ int   sTok[T];                  // 16 KB
  __shared__ float sTops[NSTACK][DEPTH];     // new stack tops (stacks_{w-1}[s][0:4])
  __shared__ float sActs[NSTACK][3];
  __shared__ float sTopv[NSTACK];
  __shared__ float sLl[8][LG];               // per-wave logit partials (deterministic)

  const int tid = threadIdx.x;
  const int b   = blockIdx.x;
  const int wv  = tid >> 6;
  const int l   = tid & 63;

  const int r0 = b * RPB + 2 * wv;
  const int r1 = r0 + 1;

  // ---- register-resident hid2hid rows (2 rows x 32 cols per lane) ----
  float wA[32], wB[32];
  {
    const float4* pa = (const float4*)(hid2hid + (size_t)r0 * NHID + 32 * l);
    const float4* pb = (const float4*)(hid2hid + (size_t)r1 * NHID + 32 * l);
#pragma unroll
    for (int j = 0; j < 8; ++j) {
      float4 v = pa[j];
      wA[4*j] = v.x; wA[4*j+1] = v.y; wA[4*j+2] = v.z; wA[4*j+3] = v.w;
    }
#pragma unroll
    for (int j = 0; j < 8; ++j) {
      float4 v = pb[j];
      wB[4*j] = v.x; wB[4*j+1] = v.y; wB[4*j+2] = v.z; wB[4*j+3] = v.w;
    }
  }
  // ---- logit weights: lane handles logits 2l, 2l+1 over rows r0,r1 ----
  float wl00, wl01, wl10, wl11;
  {
    const int lg0 = 2 * l, lg1 = 2 * l + 1;
    const float* p0 = (lg0 < 96) ? (hid2act + (size_t)lg0 * NHID)
                                 : (hid2stack + (size_t)(lg0 - 96) * STACK * NHID);
    const float* p1 = (lg1 < 96) ? (hid2act + (size_t)lg1 * NHID)
                                 : (hid2stack + (size_t)(lg1 - 96) * STACK * NHID);
    wl00 = p0[r0]; wl01 = p0[r1];
    wl10 = p1[r0]; wl11 = p1[r1];
  }
  // ---- stack2hid slice: lane covers stack cs, depths cd,cd+1 for both rows ----
  const int cs = l >> 1, cd = (l & 1) * 2;
  float w2a0, w2a1, w2b0, w2b1;
  {
    const float* p = stack2hid + (size_t)cs * NHID * STACK;
    w2a0 = p[(size_t)r0 * STACK + cd];     w2a1 = p[(size_t)r0 * STACK + cd + 1];
    w2b0 = p[(size_t)r1 * STACK + cd];     w2b1 = p[(size_t)r1 * STACK + cd + 1];
  }

  // ---- init: tokens->LDS; block0 zeroes Lmid plane 0; flag barrier ----
  for (int i = tid; i < T; i += BT) sTok[i] = tokens[i];
  if (b == 0) {
    for (int i = tid; i < LG * 8; i += BT) Lmid[i] = 0.f;
  }
  __syncthreads();
  if (tid == 0) {
    __threadfence();
    __hip_atomic_store(&flags[b], 1, __ATOMIC_RELAXED, __HIP_MEMORY_SCOPE_AGENT);
  }
  if (wv == 0) {
    int v0, v1;
    do {
      v0 = __hip_atomic_load(&flags[l],      __ATOMIC_RELAXED, __HIP_MEMORY_SCOPE_AGENT);
      v1 = __hip_atomic_load(&flags[64 + l], __ATOMIC_RELAXED, __HIP_MEMORY_SCOPE_AGENT);
    } while (!__all(v0 >= 1 && v1 >= 1));
    __threadfence();
  }
  __syncthreads();

#pragma unroll 1
  for (int w = 0; w < T; ++w) {
    const int xt = sTok[w];
    // prefetch embedding column entries for this wave's rows (uniform broadcast loads)
    const float e0 = in2hid[(size_t)r0 * NCHAR + xt];
    const float e1 = in2hid[(size_t)r1 * NCHAR + xt];

    const float* stOld = stbuf + (size_t)((w - 1) & 1) * (NSTACK * STACK);
    float*       stNew = stbuf + (size_t)(w & 1) * (NSTACK * STACK);

    // ---- A: acts/top_val/new-tops (threads 0..31), Lmid plane zero (block0) ----
    if (tid < NSTACK) {
      const int s = tid;
      if (w > 0) {
        const float* lm = Lmid + (size_t)((w - 1) % 3) * (LG * 8);
        float lgv[4];
#pragma unroll
        for (int k = 0; k < 4; ++k) {
          const int idx = (k < 3) ? (3 * s + k) : (96 + s);
          const float4* q = (const float4*)(lm + (size_t)idx * 8);
          float4 x = q[0], y = q[1];
          lgv[k] = x.x + x.y + x.z + x.w + y.x + y.y + y.z + y.w;
        }
        const float m  = fmaxf(lgv[0], fmaxf(lgv[1], lgv[2]));
        const float ea = expf(lgv[0] - m), eb = expf(lgv[1] - m), ec = expf(lgv[2] - m);
        const float inv = 1.f / (ea + eb + ec);
        const float qw = ea * inv;  // pop
        const float pw = eb * inv;  // push
        const float nw = ec * inv;  // noop
        sActs[s][0] = qw; sActs[s][1] = pw; sActs[s][2] = nw;
        float tv = lgv[3];
        tv = fminf(50.f, fmaxf(-50.f, tv));
        tv = 1.f / (1.f + expf(-tv));
        sTopv[s] = tv;
        const float o0 = stOld[s * STACK + 0], o1 = stOld[s * STACK + 1];
        const float o2 = stOld[s * STACK + 2], o3 = stOld[s * STACK + 3];
        const float o4 = stOld[s * STACK + 4];
        sTops[s][0] = pw * tv + qw * o1 + nw * o0;
        sTops[s][1] = pw * o0 + qw * o2 + nw * o1;
        sTops[s][2] = pw * o1 + qw * o3 + nw * o2;
        sTops[s][3] = pw * o2 + qw * o4 + nw * o3;
      } else {
        sActs[s][0] = sActs[s][1] = sActs[s][2] = 0.f;
        sTopv[s] = 0.f;
        sTops[s][0] = sTops[s][1] = sTops[s][2] = sTops[s][3] = -1.f;
      }
    }
    if (b == 0 && tid >= 64 && tid < 192) {
      float4* z = (float4*)(Lmid + (size_t)((w + 1) % 3) * (LG * 8) + (size_t)(tid - 64) * 8);
      z[0] = make_float4(0.f, 0.f, 0.f, 0.f);
      z[1] = make_float4(0.f, 0.f, 0.f, 0.f);
    }
    // blend operand prefetch (threads 384..511: one stack element each)
    float bo = 0.f, bom = 0.f, bop = 0.f;
    int bs = 0, bd = 0;
    if (tid >= 384) {
      const int idx = b * 128 + (tid - 384);
      bs = idx >> 9; bd = idx & 511;
      if (w > 0) {
        bo  = stOld[bs * STACK + bd];
        bom = (bd > 0)   ? stOld[bs * STACK + bd - 1] : 0.f;
        bop = (bd < 511) ? stOld[bs * STACK + bd + 1] : -1.f;
      }
    }
    __syncthreads();  // B: tops/acts ready

    // ---- C: matvec + stack contribution + sigmoid ----
    float acc0 = 0.f, acc1 = 0.f;
    if (w > 0) {
      const float4* h4 = (const float4*)(Hbuf + (size_t)(w - 1) * NHID + 32 * l);
#pragma unroll
      for (int j = 0; j < 8; ++j) {
        float4 hv = h4[j];
        acc0 += wA[4*j] * hv.x + wA[4*j+1] * hv.y + wA[4*j+2] * hv.z + wA[4*j+3] * hv.w;
        acc1 += wB[4*j] * hv.x + wB[4*j+1] * hv.y + wB[4*j+2] * hv.z + wB[4*j+3] * hv.w;
      }
    }
    acc0 += w2a0 * sTops[cs][cd] + w2a1 * sTops[cs][cd + 1];
    acc1 += w2b0 * sTops[cs][cd] + w2b1 * sTops[cs][cd + 1];
#pragma unroll
    for (int m = 1; m < 64; m <<= 1) {
      acc0 += __shfl_xor(acc0, m);
      acc1 += __shfl_xor(acc1, m);
    }
    const float h0 = 1.f / (1.f + expf(-(acc0 + e0)));
    const float h1 = 1.f / (1.f + expf(-(acc1 + e1)));
    if (l == 0) {
      *(float2*)(Hbuf + (size_t)w * NHID + r0) = make_float2(h0, h1);
    }
    // per-wave logit partials (deterministic LDS tree)
    *(float2*)&sLl[wv][2 * l] =
        make_float2(wl00 * h0 + wl01 * h1, wl10 * h0 + wl11 * h1);
    // full stack blend for this thread's element
    if (tid >= 384) {
      float v;
      if (w > 0) {
        const float qw = sActs[bs][0], pw = sActs[bs][1], nw = sActs[bs][2];
        const float pushed = (bd == 0) ? sTopv[bs] : bom;
        v = pw * pushed + qw * bop + nw * bo;
      } else {
        v = -1.f;
      }
      stNew[bs * STACK + bd] = v;
    }
    __syncthreads();  // D: h stores + sLl + blend drained per-wave

    // ---- E/F: logit reduce -> Lmid, release flag, poll; others do output dots ----
    if (wv == 0) {
      float sA = 0.f, sB = 0.f;
#pragma unroll
      for (int g = 0; g < 8; ++g) { sA += sLl[g][l]; sB += sLl[g][64 + l]; }
      float* lm = Lmid + (size_t)(w % 3) * (LG * 8);
      atomicAdd(&lm[(size_t)l * 8 + (b >> 4)], sA);
      atomicAdd(&lm[(size_t)(64 + l) * 8 + (b >> 4)], sB);
      __threadfence();
      if (tid == 0)
        __hip_atomic_store(&flags[b], w + 2, __ATOMIC_RELAXED, __HIP_MEMORY_SCOPE_AGENT);
      const int tgt = w + 2;
      int v0, v1;
      do {
        v0 = __hip_atomic_load(&flags[l],      __ATOMIC_RELAXED, __HIP_MEMORY_SCOPE_AGENT);
        v1 = __hip_atomic_load(&flags[64 + l], __ATOMIC_RELAXED, __HIP_MEMORY_SCOPE_AGENT);
      } while (!__all(v0 >= tgt && v1 >= tgt));
      __threadfence();
    } else if ((wv == 1 || wv == 2) && w > 0) {
      // deferred output logits for t = w-1 (hidden in barrier slack)
      const int c = 2 * b + (wv - 1);
      const float4* h4 = (const float4*)(Hbuf + (size_t)(w - 1) * NHID + 32 * l);
      const float4* w4 = (const float4*)(hid2out + (size_t)c * NHID + 32 * l);
      float s = 0.f;
#pragma unroll
      for (int j = 0; j < 8; ++j) {
        float4 hv = h4[j], wvv = w4[j];
        s += hv.x * wvv.x + hv.y * wvv.y + hv.z * wvv.z + hv.w * wvv.w;
      }
#pragma unroll
      for (int m = 1; m < 64; m <<= 1) s += __shfl_xor(s, m);
      if (l == 0) out[(size_t)(w - 1) * NCHAR + c] = s;
    }
    __syncthreads();  // G
  }

  // ---- tail: output logits for t = T-1 ----
  if (wv == 1 || wv == 2) {
    const int c = 2 * b + (wv - 1);
    const float4* h4 = (const float4*)(Hbuf + (size_t)(T - 1) * NHID + 32 * l);
    const float4* w4 = (const float4*)(hid2out + (size_t)c * NHID + 32 * l);
    float s = 0.f;
#pragma unroll
    for (int j = 0; j < 8; ++j) {
      float4 hv = h4[j], wvv = w4[j];
      s += hv.x * wvv.x + hv.y * wvv.y + hv.z * wvv.z + hv.w * wvv.w;
    }
#pragma unroll
    for (int m = 1; m < 64; m <<= 1) s += __shfl_xor(s, m);
    if (l == 0) out[(size_t)(T - 1) * NCHAR + c] = s;
  }
}

// ---------------- row softmax over NCHAR=256 ----------------
__global__ __launch_bounds__(64) void row_softmax(float* __restrict__ out) {
  const int t = blockIdx.x;
  const int l = threadIdx.x;
  float4* p = (float4*)(out + (size_t)t * NCHAR);
  float4 v = p[l];
  float m = fmaxf(fmaxf(v.x, v.y), fmaxf(v.z, v.w));
#pragma unroll
  for (int k = 1; k < 64; k <<= 1) m = fmaxf(m, __shfl_xor(m, k));
  const float ex = expf(v.x - m), ey = expf(v.y - m);
  const float ez = expf(v.z - m), ew = expf(v.w - m);
  float s = ex + ey + ez + ew;
#pragma unroll
  for (int k = 1; k < 64; k <<= 1) s += __shfl_xor(s, k);
  const float inv = 1.f / s;
  p[l] = make_float4(ex * inv, ey * inv, ez * inv, ew * inv);
}

extern "C" void kernel_launch(void* const* d_in, const int* in_sizes, int n_in,
                              void* d_out, int out_size, void* d_ws, size_t ws_size,
                              hipStream_t stream) {
  const int*   tokens    = (const int*)d_in[0];
  const float* in2hid    = (const float*)d_in[1];
  const float* hid2hid   = (const float*)d_in[2];
  const float* hid2act   = (const float*)d_in[3];
  const float* hid2stack = (const float*)d_in[4];
  const float* stack2hid = (const float*)d_in[5];
  const float* hid2out   = (const float*)d_in[6];
  float* out = (float*)d_out;

  float* ws    = (float*)d_ws;
  float* Hbuf  = ws;                                   // T*NHID floats
  float* stbuf = Hbuf + (size_t)T * NHID;              // 2*NSTACK*STACK
  float* Lmid  = stbuf + (size_t)2 * NSTACK * STACK;   // 3*LG*8
  int*   flags = (int*)(Lmid + (size_t)3 * LG * 8);    // NB ints

  hipLaunchKernelGGL(stackrnn_seq, dim3(NB), dim3(BT), 0, stream,
                     tokens, in2hid, hid2hid, hid2act, hid2stack, stack2hid,
                     hid2out, out, Hbuf, stbuf, Lmid, flags);
  hipLaunchKernelGGL(row_softmax, dim3(T), dim3(64), 0, stream, out);
}

// Round 2
// 41407.761 us; speedup vs baseline: 1.1117x; 1.1117x over previous
//
#include <hip/hip_runtime.h>
#include <math.h>

#define NCHAR 256
#define NHID 2048
#define NSTACK 32
#define STACK 512
#define T 4096
#define NB 128          // persistent blocks, 1 logit + 2 out-cols each
#define BT 512          // 8 waves
#define RPB 16          // hid2hid rows per block (2 per wave)
#define AGENT __HIP_MEMORY_SCOPE_AGENT

__device__ __forceinline__ float cohLoadF(const float* p) {
  return __hip_atomic_load(p, __ATOMIC_RELAXED, AGENT);
}
__device__ __forceinline__ void cohStoreF(float* p, float v) {
  __hip_atomic_store(p, v, __ATOMIC_RELAXED, AGENT);
}
// 16B coherent (cross-XCD) load: sc0 sc1 bypasses L1/L2 to the coherence point.
__device__ __forceinline__ float4 cohLoad4(const float4* p) {
  float4 r;
  asm volatile("global_load_dwordx4 %0, %1, off sc0 sc1\n\ts_waitcnt vmcnt(0)"
               : "=&v"(r) : "v"(p) : "memory");
  return r;
}

__global__ __launch_bounds__(BT) void stackrnn_seq(
    const int* __restrict__ tokens,
    const float* __restrict__ in2hid,    // [NHID][NCHAR]
    const float* __restrict__ hid2hid,   // [NHID][NHID]
    const float* __restrict__ hid2act,   // [NSTACK][3][NHID]
    const float* __restrict__ hid2stack, // [NSTACK][STACK][NHID]
    const float* __restrict__ stack2hid, // [NSTACK][NHID][STACK]
    const float* __restrict__ hid2out,   // [NCHAR][NHID]
    float* __restrict__ out,             // [T][NCHAR] logits (softmax later)
    float* __restrict__ Hbuf,            // [2][NHID]
    float* __restrict__ Lred,            // [128] reduced logits
    float* __restrict__ TopsG,           // [2][NSTACK][5] stack tops
    float* __restrict__ Halo,            // [2][NB][2] blend halo
    int*   __restrict__ flag1,           // [NB]
    int*   __restrict__ flag2)           // [NB]
{
  __shared__ int    sTok[T];             // 16 KB
  __shared__ float4 sH[576];             // h, padded idx+idx/8 (bank-conflict fix)
  __shared__ float  sActs[NSTACK][3];
  __shared__ float  sTopv[NSTACK];
  __shared__ float  sTops[NSTACK][4];
  __shared__ float  sSt[2][128];         // in-block stack neighbor exchange
  __shared__ float  sRed[8][3];          // per-wave dot partials

  const int tid = threadIdx.x;
  const int b   = blockIdx.x;
  const int wv  = tid >> 6;
  const int l   = tid & 63;
  const int r0  = b * RPB + 2 * wv;
  const int r1  = r0 + 1;

  // ---- register-resident hid2hid rows (2 rows x 32 cols per lane) ----
  float wA[32], wB[32];
  {
    const float4* pa = (const float4*)(hid2hid + (size_t)r0 * NHID + 32 * l);
    const float4* pb = (const float4*)(hid2hid + (size_t)r1 * NHID + 32 * l);
#pragma unroll
    for (int j = 0; j < 8; ++j) {
      float4 v = pa[j];
      wA[4*j] = v.x; wA[4*j+1] = v.y; wA[4*j+2] = v.z; wA[4*j+3] = v.w;
    }
#pragma unroll
    for (int j = 0; j < 8; ++j) {
      float4 v = pb[j];
      wB[4*j] = v.x; wB[4*j+1] = v.y; wB[4*j+2] = v.z; wB[4*j+3] = v.w;
    }
  }
  // ---- phase-2 weights: this block's logit row + 2 output columns ----
  const float* lrow = (b < 96) ? (hid2act + (size_t)b * NHID)
                               : (hid2stack + (size_t)(b - 96) * STACK * NHID);
  const float4 wl  = ((const float4*)lrow)[tid];
  const float4 wo0 = ((const float4*)(hid2out + (size_t)(2 * b) * NHID))[tid];
  const float4 wo1 = ((const float4*)(hid2out + (size_t)(2 * b + 1) * NHID))[tid];
  // ---- stack2hid slice: lane covers stack cs, depths cd,cd+1 ----
  const int cs = l >> 1, cd = (l & 1) * 2;
  float w2a0, w2a1, w2b0, w2b1;
  {
    const float* p = stack2hid + (size_t)cs * NHID * STACK;
    w2a0 = p[(size_t)r0 * STACK + cd]; w2a1 = p[(size_t)r0 * STACK + cd + 1];
    w2b0 = p[(size_t)r1 * STACK + cd]; w2b1 = p[(size_t)r1 * STACK + cd + 1];
  }

  for (int i = tid; i < T; i += BT) sTok[i] = tokens[i];

  // ---- stack element ownership: threads 384..511 hold one element each ----
  const int bs = b >> 2;                        // stack id
  const int bd = (b & 3) * 128 + (tid - 384);   // depth within stack
  float bval = -1.f;                            // stacks_{-1} = -1

  __syncthreads();

#pragma unroll 1
  for (int w = 0; w < T; ++w) {
    const int pw_ = w & 1, pr_ = pw_ ^ 1;       // write / read planes
    const int xt  = sTok[w];
    const float e0 = in2hid[(size_t)r0 * NCHAR + xt];
    const float e1 = in2hid[(size_t)r1 * NCHAR + xt];

    // ================= PHASE 1: h_w =================
    if (w > 0 && wv == 0) {
      int v0, v1;
      do {
        v0 = __hip_atomic_load(&flag2[l],      __ATOMIC_RELAXED, AGENT);
        v1 = __hip_atomic_load(&flag2[64 + l], __ATOMIC_RELAXED, AGENT);
      } while (__any(v0 < w || v1 < w));
    }
    __syncthreads();  // B1: all blocks' phase2(w-1) data visible

    // lead lanes: issue coherent loads (overlap with matvec below)
    float la0 = 0.f, la1 = 0.f, la2 = 0.f, lt = 0.f;
    float tg0 = 0.f, tg1 = 0.f, tg2 = 0.f, tg3 = 0.f, tg4 = 0.f;
    if (w > 0 && tid < NSTACK) {
      la0 = cohLoadF(&Lred[3 * tid]);
      la1 = cohLoadF(&Lred[3 * tid + 1]);
      la2 = cohLoadF(&Lred[3 * tid + 2]);
      lt  = cohLoadF(&Lred[96 + tid]);
      const float* tg = TopsG + ((size_t)pr_ * NSTACK + tid) * 5;
      tg0 = cohLoadF(tg);     tg1 = cohLoadF(tg + 1); tg2 = cohLoadF(tg + 2);
      tg3 = cohLoadF(tg + 3); tg4 = cohLoadF(tg + 4);
    }
    float hlv = 0.f, hrv = -1.f;
    if (w > 0) {
      if (tid == 384 && (b & 3) != 0) hlv = cohLoadF(&Halo[((size_t)pr_ * NB + b - 1) * 2 + 1]);
      if (tid == 511 && (b & 3) != 3) hrv = cohLoadF(&Halo[((size_t)pr_ * NB + b + 1) * 2]);
    }

    // matvec partial W·h_{w-1} from LDS (padded: float4 idx i -> i + i/8)
    float acc0 = 0.f, acc1 = 0.f;
    if (w > 0) {
#pragma unroll
      for (int j = 0; j < 8; ++j) {
        const float4 hv = sH[9 * l + j];
        acc0 += wA[4*j]*hv.x + wA[4*j+1]*hv.y + wA[4*j+2]*hv.z + wA[4*j+3]*hv.w;
        acc1 += wB[4*j]*hv.x + wB[4*j+1]*hv.y + wB[4*j+2]*hv.z + wB[4*j+3]*hv.w;
      }
    }

    // lead lanes: acts_{w-1}, topv, blended tops of stacks_{w-1}
    if (tid < NSTACK) {
      if (w > 0) {
        const float m  = fmaxf(la0, fmaxf(la1, la2));
        const float ea = expf(la0 - m), eb = expf(la1 - m), ec = expf(la2 - m);
        const float inv = 1.f / (ea + eb + ec);
        const float qw = ea * inv, pwt = eb * inv, nw = ec * inv; // pop,push,noop
        sActs[tid][0] = qw; sActs[tid][1] = pwt; sActs[tid][2] = nw;
        float tv = fminf(50.f, fmaxf(-50.f, lt));
        tv = 1.f / (1.f + expf(-tv));
        sTopv[tid] = tv;
        sTops[tid][0] = pwt * tv  + qw * tg1 + nw * tg0;
        sTops[tid][1] = pwt * tg0 + qw * tg2 + nw * tg1;
        sTops[tid][2] = pwt * tg1 + qw * tg3 + nw * tg2;
        sTops[tid][3] = pwt * tg2 + qw * tg4 + nw * tg3;
      } else {
        sActs[tid][0] = sActs[tid][1] = sActs[tid][2] = 0.f;
        sTopv[tid] = 0.f;
        sTops[tid][0] = sTops[tid][1] = sTops[tid][2] = sTops[tid][3] = -1.f;
      }
    }
    __syncthreads();  // B2: sActs/sTopv/sTops ready

    acc0 += w2a0 * sTops[cs][cd] + w2a1 * sTops[cs][cd + 1];
    acc1 += w2b0 * sTops[cs][cd] + w2b1 * sTops[cs][cd + 1];
#pragma unroll
    for (int m = 1; m < 64; m <<= 1) {
      acc0 += __shfl_xor(acc0, m);
      acc1 += __shfl_xor(acc1, m);
    }
    const float h0 = 1.f / (1.f + expf(-(acc0 + e0)));
    const float h1 = 1.f / (1.f + expf(-(acc1 + e1)));
    if (l == 0) {
      cohStoreF(&Hbuf[(size_t)pw_ * NHID + r0], h0);
      cohStoreF(&Hbuf[(size_t)pw_ * NHID + r1], h1);
    }

    // register-resident stack blend: stacks_{w-1} from stacks_{w-2} + acts_{w-1}
    if (tid >= 384) {
      float nv;
      if (w > 0) {
        const int j = tid - 384;
        const float leftRaw = (tid == 384) ? hlv : sSt[pr_][j - 1];
        const float pushed  = (bd == 0) ? sTopv[bs] : leftRaw;
        const float popped  = (tid == 511) ? hrv : sSt[pr_][j + 1];
        nv = sActs[bs][1] * pushed + sActs[bs][0] * popped + sActs[bs][2] * bval;
      } else {
        nv = -1.f;
      }
      bval = nv;
      sSt[pw_][tid - 384] = nv;
      if (tid == 384) cohStoreF(&Halo[((size_t)pw_ * NB + b) * 2 + 0], nv);
      if (tid == 511) cohStoreF(&Halo[((size_t)pw_ * NB + b) * 2 + 1], nv);
      if ((b & 3) == 0 && tid <= 388)  // depths 0..4 of stack bs
        cohStoreF(&TopsG[((size_t)pw_ * NSTACK + bs) * 5 + (tid - 384)], nv);
    }
    __syncthreads();  // B3: every wave drained vmcnt(0) -> all stores visible
    if (tid == 0)
      __hip_atomic_store(&flag1[b], w + 1, __ATOMIC_RELAXED, AGENT);

    // ================= PHASE 2: logits of h_w =================
    if (wv == 0) {
      int v0, v1;
      do {
        v0 = __hip_atomic_load(&flag1[l],      __ATOMIC_RELAXED, AGENT);
        v1 = __hip_atomic_load(&flag1[64 + l], __ATOMIC_RELAXED, AGENT);
      } while (__any(v0 <= w || v1 <= w));
    }
    __syncthreads();  // B4

    const float4 hv4 = cohLoad4((const float4*)(Hbuf + (size_t)pw_ * NHID) + tid);
    sH[tid + (tid >> 3)] = hv4;   // cache h_w for next step's matvec
    float d0 = wl.x  * hv4.x + wl.y  * hv4.y + wl.z  * hv4.z + wl.w  * hv4.w;
    float d1 = wo0.x * hv4.x + wo0.y * hv4.y + wo0.z * hv4.z + wo0.w * hv4.w;
    float d2 = wo1.x * hv4.x + wo1.y * hv4.y + wo1.z * hv4.z + wo1.w * hv4.w;
#pragma unroll
    for (int m = 1; m < 64; m <<= 1) {
      d0 += __shfl_xor(d0, m);
      d1 += __shfl_xor(d1, m);
      d2 += __shfl_xor(d2, m);
    }
    if (l == 0) { sRed[wv][0] = d0; sRed[wv][1] = d1; sRed[wv][2] = d2; }
    __syncthreads();  // B5
    if (tid == 0) {
      float s0 = 0.f, s1 = 0.f, s2 = 0.f;
#pragma unroll
      for (int g = 0; g < 8; ++g) {
        s0 += sRed[g][0]; s1 += sRed[g][1]; s2 += sRed[g][2];
      }
      cohStoreF(&Lred[b], s0);
      cohStoreF(&out[(size_t)w * NCHAR + 2 * b],     s1);
      cohStoreF(&out[(size_t)w * NCHAR + 2 * b + 1], s2);
      asm volatile("s_waitcnt vmcnt(0)" ::: "memory");  // own stores complete
      __hip_atomic_store(&flag2[b], w + 1, __ATOMIC_RELAXED, AGENT);
    }
  }
}

// ---------------- row softmax over NCHAR=256 ----------------
__global__ __launch_bounds__(64) void row_softmax(float* __restrict__ out) {
  const int t = blockIdx.x;
  const int l = threadIdx.x;
  float4* p = (float4*)(out + (size_t)t * NCHAR);
  float4 v = p[l];
  float m = fmaxf(fmaxf(v.x, v.y), fmaxf(v.z, v.w));
#pragma unroll
  for (int k = 1; k < 64; k <<= 1) m = fmaxf(m, __shfl_xor(m, k));
  const float ex = expf(v.x - m), ey = expf(v.y - m);
  const float ez = expf(v.z - m), ew = expf(v.w - m);
  float s = ex + ey + ez + ew;
#pragma unroll
  for (int k = 1; k < 64; k <<= 1) s += __shfl_xor(s, k);
  const float inv = 1.f / s;
  p[l] = make_float4(ex * inv, ey * inv, ez * inv, ew * inv);
}

extern "C" void kernel_launch(void* const* d_in, const int* in_sizes, int n_in,
                              void* d_out, int out_size, void* d_ws, size_t ws_size,
                              hipStream_t stream) {
  const int*   tokens    = (const int*)d_in[0];
  const float* in2hid    = (const float*)d_in[1];
  const float* hid2hid   = (const float*)d_in[2];
  const float* hid2act   = (const float*)d_in[3];
  const float* hid2stack = (const float*)d_in[4];
  const float* stack2hid = (const float*)d_in[5];
  const float* hid2out   = (const float*)d_in[6];
  float* out = (float*)d_out;

  float* ws    = (float*)d_ws;
  float* Hbuf  = ws;                         // 2*NHID = 4096
  float* Lred  = Hbuf + 2 * NHID;            // 128
  float* TopsG = Lred + 128;                 // 2*32*5 = 320
  float* Halo  = TopsG + 320;                // 2*NB*2 = 512
  int*   flag1 = (int*)(Halo + 512);         // NB
  int*   flag2 = flag1 + NB;                 // NB

  hipLaunchKernelGGL(stackrnn_seq, dim3(NB), dim3(BT), 0, stream,
                     tokens, in2hid, hid2hid, hid2act, hid2stack, stack2hid,
                     hid2out, out, Hbuf, Lred, TopsG, Halo, flag1, flag2);
  hipLaunchKernelGGL(row_softmax, dim3(T), dim3(64), 0, stream, out);
}